// Round 8
// baseline (77.266 us; speedup 1.0000x reference)
//
#include <hip/hip_runtime.h>
#include <hip/hip_cooperative_groups.h>
#include <math.h>

#define H 1024
#define B 128
#define KSP 32           // K-split; BK = H/KSP
#define BK 32
#define BN 128           // N-tile; 8 n-tiles
#define LP 132           // padded LDS row (f32)

typedef unsigned short u16;
typedef unsigned int u32;

static __device__ inline u16 f2bf(float x) {
    u32 u = __builtin_bit_cast(u32, x);
    return (u16)((u + 0x7FFFu + ((u >> 16) & 1u)) >> 16);   // RTNE
}
static __device__ inline float bf2f(u16 h) {
    return __builtin_bit_cast(float, (u32)h << 16);
}

// Single cooperative kernel: 256 blocks x 256 threads.
// ws: invS (4 KB) | partial bf16 [KSP][B*H] (8 MB)
__global__ __launch_bounds__(256) void kfused(const float* __restrict__ A,
                                              const float* __restrict__ U,
                                              float* __restrict__ invS,
                                              u16* __restrict__ partial,
                                              float* __restrict__ out) {
    const int t   = threadIdx.x;
    const int bid = blockIdx.x;          // 0..255
    cooperative_groups::grid_group gg = cooperative_groups::this_grid();

    // ---- phase 1: invS[r] = 1/sum_j exp(U[r][j]); 4 rows/block, 1 per wave ----
    {
        const int w = t >> 6, l = t & 63;
        const int r = bid * 4 + w;
        const float* Urow = U + (size_t)r * H;
        float s = 0.f;
        #pragma unroll
        for (int c = 0; c < 4; ++c) {
            float4 u4 = *reinterpret_cast<const float4*>(Urow + c * 256 + l * 4);
            s += __expf(u4.x) + __expf(u4.y) + __expf(u4.z) + __expf(u4.w);
        }
        #pragma unroll
        for (int off = 32; off > 0; off >>= 1) s += __shfl_down(s, off, 64);
        if (l == 0) invS[r] = 1.0f / s;
    }
    gg.sync();

    // ---- phase 2: partial[ks][b][j] = sum_{k in slice} exp(A[b][k])*exp(U[k][j])*invS[k]
    {
        const int j0 = (bid & 7) * BN;
        const int ks = bid >> 3;
        const int k0 = ks * BK;

        __shared__ float Pl[BK][LP];   // Pl[k][b] = exp(A[b][k0+k])
        __shared__ float Ql[BK][LP];   // Ql[k][j] = exp(U[k0+k][j0+j]) * invS[k0+k]

        {   // stage P (transposed scatter)
            const int c = (t & 7) * 4;
            #pragma unroll
            for (int p = 0; p < 4; ++p) {
                const int b = (t >> 3) + 32 * p;
                float4 a = *reinterpret_cast<const float4*>(A + (size_t)b * H + k0 + c);
                Pl[c + 0][b] = __expf(a.x);
                Pl[c + 1][b] = __expf(a.y);
                Pl[c + 2][b] = __expf(a.z);
                Pl[c + 3][b] = __expf(a.w);
            }
        }
        {   // stage Q (natural)
            const int k = t >> 3;
            const float is = invS[k0 + k];
            const float* Urow = U + (size_t)(k0 + k) * H + j0;
            #pragma unroll
            for (int p = 0; p < 4; ++p) {
                const int j = (t & 7) * 4 + 32 * p;
                float4 u = *reinterpret_cast<const float4*>(Urow + j);
                float4 q;
                q.x = __expf(u.x) * is;
                q.y = __expf(u.y) * is;
                q.z = __expf(u.z) * is;
                q.w = __expf(u.w) * is;
                *reinterpret_cast<float4*>(&Ql[k][j]) = q;
            }
        }
        __syncthreads();

        const int tb = t >> 4;
        const int tj = t & 15;

        float acc[8][8];
        #pragma unroll
        for (int i = 0; i < 8; ++i)
            #pragma unroll
            for (int j = 0; j < 8; ++j) acc[i][j] = 0.0f;

        #pragma unroll 4
        for (int kk = 0; kk < BK; ++kk) {
            float4 p0 = *reinterpret_cast<const float4*>(&Pl[kk][tb * 8]);
            float4 p1 = *reinterpret_cast<const float4*>(&Pl[kk][tb * 8 + 4]);
            float4 q0 = *reinterpret_cast<const float4*>(&Ql[kk][tj * 8]);
            float4 q1 = *reinterpret_cast<const float4*>(&Ql[kk][tj * 8 + 4]);
            float pr[8] = {p0.x, p0.y, p0.z, p0.w, p1.x, p1.y, p1.z, p1.w};
            float qr[8] = {q0.x, q0.y, q0.z, q0.w, q1.x, q1.y, q1.z, q1.w};
            #pragma unroll
            for (int i = 0; i < 8; ++i)
                #pragma unroll
                for (int j = 0; j < 8; ++j)
                    acc[i][j] = fmaf(pr[i], qr[j], acc[i][j]);
        }

        u16* pbase = partial + (size_t)ks * (B * H) + j0 + tj * 8;
        #pragma unroll
        for (int i = 0; i < 8; ++i) {
            const int b = tb * 8 + i;
            uint4 v;
            v.x = (u32)f2bf(acc[i][0]) | ((u32)f2bf(acc[i][1]) << 16);
            v.y = (u32)f2bf(acc[i][2]) | ((u32)f2bf(acc[i][3]) << 16);
            v.z = (u32)f2bf(acc[i][4]) | ((u32)f2bf(acc[i][5]) << 16);
            v.w = (u32)f2bf(acc[i][6]) | ((u32)f2bf(acc[i][7]) << 16);
            *reinterpret_cast<uint4*>(pbase + (size_t)b * H) = v;
        }
    }
    gg.sync();

    // ---- phase 3: out = log(sum_ks partial), 2 outputs/thread ----
    {
        const int idx2 = (bid * 256 + t) * 2;
        float s0 = 0.f, s1 = 0.f;
        #pragma unroll 8
        for (int ks = 0; ks < KSP; ++ks) {
            ushort2 q = *reinterpret_cast<const ushort2*>(partial + ((size_t)ks << 17) + idx2);
            s0 += bf2f(q.x);
            s1 += bf2f(q.y);
        }
        float2 o;
        o.x = __logf(s0);
        o.y = __logf(s1);
        *reinterpret_cast<float2*>(out + idx2) = o;
    }
}

extern "C" void kernel_launch(void* const* d_in, const int* in_sizes, int n_in,
                              void* d_out, int out_size, void* d_ws, size_t ws_size,
                              hipStream_t stream) {
    const float* A = (const float*)d_in[0];   // log_alpha (128 x 1024)
    const float* U = (const float*)d_in[1];   // unnormalized_tran (1024 x 1024)
    float* out = (float*)d_out;               // (128 x 1024) f32

    char* ws = (char*)d_ws;
    float* invS  = (float*)ws;                 // 4 KB
    u16* partial = (u16*)(ws + 4096);          // 8 MB

    void* args[] = {(void*)&A, (void*)&U, (void*)&invS, (void*)&partial, (void*)&out};
    hipLaunchCooperativeKernel(reinterpret_cast<void*>(kfused),
                               dim3(256), dim3(256), args, 0, stream);
}

// Round 9
// 22.163 us; speedup vs baseline: 3.4863x; 3.4863x over previous
//
#include <hip/hip_runtime.h>
#include <math.h>

#define H 1024
#define B 128
#define BM 16            // b-rows per block
#define BN 32            // j-cols per block
#define BKS 64           // K per staging step
#define NSTEP (H / BKS)  // 16
#define PROW 72          // padded LDS row (bf16 units); 144 B, bank-stride 4

typedef unsigned short u16;
typedef unsigned int u32;
typedef __attribute__((ext_vector_type(8))) short bf16x8;
typedef __attribute__((ext_vector_type(4))) float f32x4;

static __device__ inline u16 f2bf(float x) {
    u32 u = __builtin_bit_cast(u32, x);
    return (u16)((u + 0x7FFFu + ((u >> 16) & 1u)) >> 16);   // RTNE
}
static __device__ inline u32 pack2(u16 a, u16 b) { return (u32)a | ((u32)b << 16); }

// ---- k1: lse[r] = log sum_j exp(U[r][j]); 4 rows/block, one per wave ------
__global__ __launch_bounds__(256) void k_lse(const float* __restrict__ U,
                                             float* __restrict__ lse) {
    const int w = threadIdx.x >> 6, l = threadIdx.x & 63;
    const int r = blockIdx.x * 4 + w;
    const float* Urow = U + (size_t)r * H;
    float s = 0.f;
    #pragma unroll
    for (int c = 0; c < 4; ++c) {
        float4 u4 = *reinterpret_cast<const float4*>(Urow + c * 256 + l * 4);
        s += __expf(u4.x) + __expf(u4.y) + __expf(u4.z) + __expf(u4.w);
    }
    #pragma unroll
    for (int off = 32; off > 0; off >>= 1) s += __shfl_down(s, off, 64);
    if (l == 0) lse[r] = __logf(s);
}

// ---- k2: out[b][j] = log( sum_k exp(A[b][k]-lse[k]) * exp(U[k][j]) ) ------
// full-K per block; 4 waves = (kh in 2 K-halves) x (jh in 2 j-halves)
__global__ __launch_bounds__(256) void k_mm(const float* __restrict__ A,
                                            const float* __restrict__ U,
                                            const float* __restrict__ lse,
                                            float* __restrict__ out) {
    __shared__ __align__(16) u16 Pl[BM][PROW];   // P'[b][k] bf16
    __shared__ __align__(16) u16 Qt[BN][PROW];   // Q^T[j][k] bf16
    __shared__ float red[2][16][17];             // kh=1 partial, per jh

    const int t  = threadIdx.x;
    const int b0 = blockIdx.x * BM;   // 0..7  -> b
    const int j0 = blockIdx.y * BN;   // 0..31 -> j
    const int l  = t & 63, w = t >> 6;
    const int jh = w & 1, kh = w >> 1;

    // staging maps
    const int pb  = t >> 4;           // 0..15   P row (b)
    const int pk  = (t & 15) * 4;     // k quad for P
    const int qkp = t >> 3;           // 0..31   k-pair index for Q
    const int qje = (t & 7) * 4;      // j quad for Q

    f32x4 acc = {0.f, 0.f, 0.f, 0.f};

    for (int s = 0; s < NSTEP; ++s) {
        const int k0 = s * BKS;
        // stage P': exp(A[b][k] - lse[k]) -> Pl[b][k]   (4 elems/thread)
        {
            float4 a4 = *reinterpret_cast<const float4*>(A + (size_t)(b0 + pb) * H + k0 + pk);
            float4 l4 = *reinterpret_cast<const float4*>(lse + k0 + pk);
            uint2 wv;
            wv.x = pack2(f2bf(__expf(a4.x - l4.x)), f2bf(__expf(a4.y - l4.y)));
            wv.y = pack2(f2bf(__expf(a4.z - l4.z)), f2bf(__expf(a4.w - l4.w)));
            *reinterpret_cast<uint2*>(&Pl[pb][pk]) = wv;
        }
        // stage Q^T: exp(U[k][j]) -> Qt[j][k]   (2 k x 4 j per thread)
        {
            const int k = k0 + qkp * 2;
            float4 u0 = *reinterpret_cast<const float4*>(U + (size_t)k * H + j0 + qje);
            float4 u1 = *reinterpret_cast<const float4*>(U + (size_t)(k + 1) * H + j0 + qje);
            *reinterpret_cast<u32*>(&Qt[qje + 0][qkp * 2]) = pack2(f2bf(__expf(u0.x)), f2bf(__expf(u1.x)));
            *reinterpret_cast<u32*>(&Qt[qje + 1][qkp * 2]) = pack2(f2bf(__expf(u0.y)), f2bf(__expf(u1.y)));
            *reinterpret_cast<u32*>(&Qt[qje + 2][qkp * 2]) = pack2(f2bf(__expf(u0.z)), f2bf(__expf(u1.z)));
            *reinterpret_cast<u32*>(&Qt[qje + 3][qkp * 2]) = pack2(f2bf(__expf(u0.w)), f2bf(__expf(u1.w)));
        }
        __syncthreads();
        // one MFMA per wave per step: wave's K-half slice of this K-step
        {
            const int kk = kh * 32 + (l >> 4) * 8;
            bf16x8 af = *reinterpret_cast<const bf16x8*>(&Pl[l & 15][kk]);
            bf16x8 bfv = *reinterpret_cast<const bf16x8*>(&Qt[jh * 16 + (l & 15)][kk]);
            acc = __builtin_amdgcn_mfma_f32_16x16x32_bf16(af, bfv, acc, 0, 0, 0);
        }
        __syncthreads();
    }

    // reduce the two K-halves, then log + store
    if (kh == 1) {
        #pragma unroll
        for (int r = 0; r < 4; ++r)
            red[jh][(l >> 4) * 4 + r][l & 15] = acc[r];
    }
    __syncthreads();
    if (kh == 0) {
        #pragma unroll
        for (int r = 0; r < 4; ++r) {
            const int row = (l >> 4) * 4 + r;
            const float v = acc[r] + red[jh][row][l & 15];
            out[(size_t)(b0 + row) * H + j0 + jh * 16 + (l & 15)] = __logf(v);
        }
    }
}

extern "C" void kernel_launch(void* const* d_in, const int* in_sizes, int n_in,
                              void* d_out, int out_size, void* d_ws, size_t ws_size,
                              hipStream_t stream) {
    const float* A = (const float*)d_in[0];   // log_alpha (128 x 1024)
    const float* U = (const float*)d_in[1];   // unnormalized_tran (1024 x 1024)
    float* out = (float*)d_out;               // (128 x 1024) f32

    float* lse = (float*)d_ws;                // 4 KB scratch

    k_lse<<<H / 4, 256, 0, stream>>>(U, lse);
    dim3 g(B / BM, H / BN);                   // (8, 32) = 256 blocks
    k_mm<<<g, 256, 0, stream>>>(A, U, lse, out);
}

// Round 10
// 16.255 us; speedup vs baseline: 4.7535x; 1.3635x over previous
//
#include <hip/hip_runtime.h>
#include <hip/hip_bf16.h>
#include <math.h>

#define H 1024
#define B 128
#define PROW 1032   // padded LDS row for P' (bf16 units); 2064 B, 16B-aligned

typedef unsigned short u16;
typedef unsigned int u32;
typedef __attribute__((ext_vector_type(8))) short bf16x8;
typedef __attribute__((ext_vector_type(4))) float f32x4;

static __device__ inline u16 f2bf(float x) {
    __hip_bfloat16 h = __float2bfloat16(x);   // RTNE; compiler pairs into v_cvt_pk_bf16_f32
    return __builtin_bit_cast(u16, h);
}

// ---- k1: expU[r][j] = bf16(exp(U[r][j])); invS[r] = 1/sum_j exp(U[r][j]) --
// 4 rows/block (one per wave), 256 blocks.
__global__ __launch_bounds__(256) void k1(const float* __restrict__ U,
                                          u16* __restrict__ expU,
                                          float* __restrict__ invS) {
    const int w = threadIdx.x >> 6, l = threadIdx.x & 63;
    const int r = blockIdx.x * 4 + w;
    const float* Ur = U + (size_t)r * H;
    u16* Er = expU + (size_t)r * H;
    float s = 0.f;
    #pragma unroll
    for (int c = 0; c < 4; ++c) {
        float4 u4 = *reinterpret_cast<const float4*>(Ur + c * 256 + l * 4);
        float e0 = __expf(u4.x), e1 = __expf(u4.y), e2 = __expf(u4.z), e3 = __expf(u4.w);
        s += e0 + e1 + e2 + e3;
        ushort4 o = {f2bf(e0), f2bf(e1), f2bf(e2), f2bf(e3)};
        *reinterpret_cast<ushort4*>(Er + c * 256 + l * 4) = o;
    }
    #pragma unroll
    for (int off = 32; off > 0; off >>= 1) s += __shfl_down(s, off, 64);
    if (l == 0) invS[r] = 1.0f / s;
}

// ---- k2: out[b][j] = log( sum_k (exp(A[b][k])*invS[k]) * expU[k][j] ) -----
// grid (8,32) = 256 blocks, 512 threads = 8 waves: kh in {0..3} (K-split),
// jh in {0,1} (j-half). B-fragments gathered directly from expU (L2-hot).
__global__ __launch_bounds__(512) void k2(const float* __restrict__ A,
                                          const u16* __restrict__ expU,
                                          const float* __restrict__ invS,
                                          float* __restrict__ out) {
    __shared__ __align__(16) u16 Pl[16][PROW];     // P'[b][k] bf16, 33 KB
    __shared__ float red[3][2][16][16];            // kh=1..3 partials, 6 KB

    const int t  = threadIdx.x;
    const int b0 = blockIdx.x * 16;   // 8 b-tiles
    const int j0 = blockIdx.y * 32;   // 32 j-tiles
    const int l  = t & 63, w = t >> 6;
    const int jh = w & 1, kh = w >> 1;

    // ---- stage P' = exp(A)*invS, once (16 rows x 1024 k) ----
    {
        const int b  = t >> 5;          // 0..15
        const int kq = (t & 31) * 4;    // k quad base
        #pragma unroll
        for (int pass = 0; pass < 8; ++pass) {
            const int k = kq + pass * 128;
            float4 a4 = *reinterpret_cast<const float4*>(A + (size_t)(b0 + b) * H + k);
            float4 s4 = *reinterpret_cast<const float4*>(invS + k);
            ushort4 o = {f2bf(__expf(a4.x) * s4.x), f2bf(__expf(a4.y) * s4.y),
                         f2bf(__expf(a4.z) * s4.z), f2bf(__expf(a4.w) * s4.w)};
            *reinterpret_cast<ushort4*>(&Pl[b][k]) = o;
        }
    }
    __syncthreads();

    // ---- K loop: 8 steps, no barriers; 1 MFMA per wave per step ----
    f32x4 acc = {0.f, 0.f, 0.f, 0.f};
    const int col  = j0 + jh * 16 + (l & 15);
    const int krow = (l >> 4) * 8;

    #pragma unroll 2
    for (int s = 0; s < 8; ++s) {
        const int kk = s * 128 + kh * 32 + krow;
        bf16x8 af = *reinterpret_cast<const bf16x8*>(&Pl[l & 15][kk]);
        const u16* bp = expU + (size_t)kk * H + col;
        u32 w0 = (u32)bp[0 * H] | ((u32)bp[1 * H] << 16);
        u32 w1 = (u32)bp[2 * H] | ((u32)bp[3 * H] << 16);
        u32 w2 = (u32)bp[4 * H] | ((u32)bp[5 * H] << 16);
        u32 w3 = (u32)bp[6 * H] | ((u32)bp[7 * H] << 16);
        uint4 bw = {w0, w1, w2, w3};
        bf16x8 bfr = __builtin_bit_cast(bf16x8, bw);
        acc = __builtin_amdgcn_mfma_f32_16x16x32_bf16(af, bfr, acc, 0, 0, 0);
    }

    // ---- reduce 4 K-splits, log, store ----
    if (kh != 0) {
        #pragma unroll
        for (int r = 0; r < 4; ++r)
            red[kh - 1][jh][(l >> 4) * 4 + r][l & 15] = acc[r];
    }
    __syncthreads();
    if (kh == 0) {
        #pragma unroll
        for (int r = 0; r < 4; ++r) {
            const int row = (l >> 4) * 4 + r;
            const float v = acc[r] + red[0][jh][row][l & 15]
                                   + red[1][jh][row][l & 15]
                                   + red[2][jh][row][l & 15];
            out[(size_t)(b0 + row) * H + col] = __logf(v);
        }
    }
}

extern "C" void kernel_launch(void* const* d_in, const int* in_sizes, int n_in,
                              void* d_out, int out_size, void* d_ws, size_t ws_size,
                              hipStream_t stream) {
    const float* A = (const float*)d_in[0];   // log_alpha (128 x 1024)
    const float* U = (const float*)d_in[1];   // unnormalized_tran (1024 x 1024)
    float* out = (float*)d_out;               // (128 x 1024) f32

    char* ws = (char*)d_ws;
    float* invS = (float*)ws;                 // 4 KB
    u16* expU   = (u16*)(ws + 4096);          // 2 MB

    k1<<<H / 4, 256, 0, stream>>>(U, expU, invS);
    dim3 g(B / 16, H / 32);                   // (8, 32) = 256 blocks
    k2<<<g, 512, 0, stream>>>(A, expU, invS, out);
}

// Round 11
// 14.013 us; speedup vs baseline: 5.5137x; 1.1599x over previous
//
#include <hip/hip_runtime.h>
#include <hip/hip_bf16.h>

#define H 1024
#define B 128

typedef unsigned short u16;
typedef unsigned int u32;
typedef __attribute__((ext_vector_type(8))) short bf16x8;
typedef __attribute__((ext_vector_type(4))) float f32x4;

static __device__ inline u16 f2bf(float x) {
    __hip_bfloat16 h = __float2bfloat16(x);   // RTNE -> v_cvt_pk_bf16_f32 pairs
    return __builtin_bit_cast(u16, h);
}

// ---- k1 -------------------------------------------------------------------
// blocks 0..127 : 8 U-rows each. Q[k][j] = exp(U[k][j]) / S[k]  (invS folded
//                 here — each wave owns a row, so S is wave-local).
//                 Written in MFMA-B-packed layout expUP[k>>3][j][k&7] (bf16)
//                 via LDS transpose; 16B coalesced packed stores.
// blocks 128..159: 4 A-rows each -> expA[b][k] = exp(A[b][k]) bf16 row-major.
__global__ __launch_bounds__(256) void k1(const float* __restrict__ A,
                                          const float* __restrict__ U,
                                          u16* __restrict__ expUP,
                                          u16* __restrict__ expA) {
    const int t = threadIdx.x, w = t >> 6, l = t & 63;
    const int blk = blockIdx.x;
    if (blk < 128) {
        __shared__ u16 Lq[8][1024];   // 16 KB
        #pragma unroll
        for (int rr = 0; rr < 2; ++rr) {
            const int row = w * 2 + rr;                       // 0..7
            const float* Ur = U + (size_t)(blk * 8 + row) * H;
            float e[16];
            float s = 0.f;
            #pragma unroll
            for (int c = 0; c < 4; ++c) {
                float4 u4 = *reinterpret_cast<const float4*>(Ur + c * 256 + l * 4);
                e[c*4+0] = __expf(u4.x); e[c*4+1] = __expf(u4.y);
                e[c*4+2] = __expf(u4.z); e[c*4+3] = __expf(u4.w);
                s += e[c*4+0] + e[c*4+1] + e[c*4+2] + e[c*4+3];
            }
            #pragma unroll
            for (int off = 32; off > 0; off >>= 1) s += __shfl_down(s, off, 64);
            const float is = 1.0f / __shfl(s, 0, 64);
            #pragma unroll
            for (int c = 0; c < 4; ++c) {
                ushort4 o = {f2bf(e[c*4+0]*is), f2bf(e[c*4+1]*is),
                             f2bf(e[c*4+2]*is), f2bf(e[c*4+3]*is)};
                *reinterpret_cast<ushort4*>(&Lq[row][c*256 + l*4]) = o;
            }
        }
        __syncthreads();
        // packed write-out: this block owns k-group (blk) -> [1024 j][8 k]
        u16* dst = expUP + (size_t)blk * (H * 8);
        #pragma unroll
        for (int c = 0; c < 4; ++c) {
            const int j = c * 256 + t;
            uint4 v;
            v.x = (u32)Lq[0][j] | ((u32)Lq[1][j] << 16);
            v.y = (u32)Lq[2][j] | ((u32)Lq[3][j] << 16);
            v.z = (u32)Lq[4][j] | ((u32)Lq[5][j] << 16);
            v.w = (u32)Lq[6][j] | ((u32)Lq[7][j] << 16);
            *reinterpret_cast<uint4*>(dst + (size_t)j * 8) = v;
        }
    } else {
        const int b = (blk - 128) * 4 + w;
        const float* Ar = A + (size_t)b * H;
        u16* Er = expA + (size_t)b * H;
        #pragma unroll
        for (int c = 0; c < 4; ++c) {
            float4 a4 = *reinterpret_cast<const float4*>(Ar + c * 256 + l * 4);
            ushort4 o = {f2bf(__expf(a4.x)), f2bf(__expf(a4.y)),
                         f2bf(__expf(a4.z)), f2bf(__expf(a4.w))};
            *reinterpret_cast<ushort4*>(Er + c * 256 + l * 4) = o;
        }
    }
}

// ---- k2: out[b][j] = log( sum_k expA[b][k] * Q[k][j] ) --------------------
// grid (8,32) = 256 blocks x 512 threads = 8 waves: kh in 0..3 (K-split),
// jh in 0..1. Pure load+MFMA K-loop: no exp, no staging, no barriers.
__global__ __launch_bounds__(512) void k2(const u16* __restrict__ expA,
                                          const u16* __restrict__ expUP,
                                          float* __restrict__ out) {
    __shared__ float red[4][2][4][66];   // [kh][jh][r][lane] f32, pad 66
    const int t = threadIdx.x, l = t & 63, w = t >> 6;
    const int jh = w & 1, kh = w >> 1;
    const int b0 = blockIdx.x * 16;
    const int j0 = blockIdx.y * 32;
    const int colJ = j0 + jh * 16 + (l & 15);
    const int arow = b0 + (l & 15);
    const int kg   = l >> 4;              // 0..3

    f32x4 acc = {0.f, 0.f, 0.f, 0.f};
    #pragma unroll
    for (int s = 0; s < 8; ++s) {
        const int kk = s * 128 + kh * 32 + kg * 8;
        bf16x8 af = *reinterpret_cast<const bf16x8*>(expA + (size_t)arow * H + kk);
        bf16x8 bfv = *reinterpret_cast<const bf16x8*>(expUP + ((size_t)(kk >> 3) * H + colJ) * 8);
        acc = __builtin_amdgcn_mfma_f32_16x16x32_bf16(af, bfv, acc, 0, 0, 0);
    }

    #pragma unroll
    for (int r = 0; r < 4; ++r) red[kh][jh][r][l] = acc[r];
    __syncthreads();

    // one output per thread: row = t>>5 (0..15), c = t&31
    const int row = t >> 5, c = t & 31;
    const int jj = c >> 4, cc = c & 15;
    const int ll = (row >> 2) * 16 + cc, r = row & 3;
    const float v = red[0][jj][r][ll] + red[1][jj][r][ll]
                  + red[2][jj][r][ll] + red[3][jj][r][ll];
    out[(size_t)(b0 + row) * H + j0 + c] = __logf(v);
}

extern "C" void kernel_launch(void* const* d_in, const int* in_sizes, int n_in,
                              void* d_out, int out_size, void* d_ws, size_t ws_size,
                              hipStream_t stream) {
    const float* A = (const float*)d_in[0];   // log_alpha (128 x 1024)
    const float* U = (const float*)d_in[1];   // unnormalized_tran (1024 x 1024)
    float* out = (float*)d_out;               // (128 x 1024) f32

    char* ws = (char*)d_ws;
    u16* expUP = (u16*)ws;                        // 2 MB  packed Q bf16
    u16* expA  = (u16*)(ws + (size_t)2 * 1024 * 1024);  // 256 KB exp(A) bf16

    k1<<<160, 256, 0, stream>>>(A, U, expUP, expA);
    dim3 g(B / 16, H / 32);                   // (8, 32) = 256 blocks
    k2<<<g, 512, 0, stream>>>(expA, expUP, out);
}